// Round 1
// baseline (267.010 us; speedup 1.0000x reference)
//
#include <hip/hip_runtime.h>

#define TLEN   6000
#define NV4    1500          // TLEN / 4
#define NTILES 24            // ceil(NV4 / 64)
#define LN_EPS (-13.815511f) // ln(1e-6)
#define INV_EPS 1e6f

__device__ __forceinline__ float pcen_out(float xv, float M, float alpha,
                                          float delta, float r, float deltar) {
    // gain = exp(-alpha * (ln(eps) + log1p(M/eps)))
    float gain = __expf(-alpha * (LN_EPS + __logf(fmaf(M, INV_EPS, 1.0f))));
    return __powf(fmaf(xv, gain, delta), r) - deltar;
}

__global__ __launch_bounds__(256, 4) void pcen_kernel(
    const float* __restrict__ x,
    const float* __restrict__ log_s,
    const float* __restrict__ log_alpha,
    const float* __restrict__ log_delta,
    const float* __restrict__ log_r,
    float* __restrict__ out,
    int num_series)
{
    const int wave = (int)((blockIdx.x * blockDim.x + threadIdx.x) >> 6);
    const int lane = (int)(threadIdx.x & 63);
    if (wave >= num_series) return;

    const int f = wave & 127;  // series = b*F + f (C==1, F==128)

    const float s      = __expf(log_s[f]);
    const float alpha  = __expf(log_alpha[f]);
    const float delta  = __expf(log_delta[f]);
    const float r      = __expf(log_r[f]);
    const float oms    = 1.0f - s;
    const float deltar = __powf(delta, r);

    const float4* __restrict__ xb = (const float4*)(x + (size_t)wave * TLEN);
    float4* __restrict__ ob       = (float4*)(out + (size_t)wave * TLEN);

    float Mc = 0.0f;  // smoother value entering current tile (dummy before t=0)

    int  vidx  = lane;
    bool valid = vidx < NV4;
    float4 xv  = valid ? xb[vidx] : make_float4(0.f, 0.f, 0.f, 0.f);

    for (int tile = 0; tile < NTILES; ++tile) {
        // ---- prefetch next tile ----
        const int  nvidx  = vidx + 64;
        const bool nvalid = nvidx < NV4;
        float4 xn = nvalid ? xb[nvidx] : make_float4(0.f, 0.f, 0.f, 0.f);

        // ---- local affine over this lane's 4 timesteps ----
        // element t affine: t==0 -> (0, x0)  (M_0 = x_0), else (1-s, s*x_t)
        float A, B;
        if (valid) {
            if (vidx == 0) { A = 0.0f; B = xv.x; }
            else           { A = oms;  B = s * xv.x; }
            B = fmaf(oms, B, s * xv.y); A *= oms;
            B = fmaf(oms, B, s * xv.z); A *= oms;
            B = fmaf(oms, B, s * xv.w); A *= oms;
        } else {
            A = 1.0f; B = 0.0f;  // identity
        }

        // ---- inclusive wave scan of affine composition ----
        #pragma unroll
        for (int off = 1; off < 64; off <<= 1) {
            float Ap = __shfl_up(A, off, 64);
            float Bp = __shfl_up(B, off, 64);
            if (lane >= off) { B = fmaf(A, Bp, B); A = A * Ap; }
        }

        // tile-total composition (lane 63) for the carry
        const float A63 = __shfl(A, 63, 64);
        const float B63 = __shfl(B, 63, 64);

        // exclusive prefix for this lane
        float Ae = __shfl_up(A, 1, 64);
        float Be = __shfl_up(B, 1, 64);
        if (lane == 0) { Ae = 1.0f; Be = 0.0f; }

        // ---- apply + epilogue ----
        if (valid) {
            float M = fmaf(Ae, Mc, Be);  // smoother entering this lane's group
            float4 o;
            float a0, b0;
            if (vidx == 0) { a0 = 0.0f; b0 = xv.x; }
            else           { a0 = oms;  b0 = s * xv.x; }
            M = fmaf(a0, M, b0);
            o.x = pcen_out(xv.x, M, alpha, delta, r, deltar);
            M = fmaf(oms, M, s * xv.y);
            o.y = pcen_out(xv.y, M, alpha, delta, r, deltar);
            M = fmaf(oms, M, s * xv.z);
            o.z = pcen_out(xv.z, M, alpha, delta, r, deltar);
            M = fmaf(oms, M, s * xv.w);
            o.w = pcen_out(xv.w, M, alpha, delta, r, deltar);
            ob[vidx] = o;
        }

        // ---- advance carry & tile ----
        Mc    = fmaf(A63, Mc, B63);
        vidx  = nvidx;
        valid = nvalid;
        xv    = xn;
    }
}

extern "C" void kernel_launch(void* const* d_in, const int* in_sizes, int n_in,
                              void* d_out, int out_size, void* d_ws, size_t ws_size,
                              hipStream_t stream) {
    const float* x         = (const float*)d_in[0];
    const float* log_s     = (const float*)d_in[1];
    const float* log_alpha = (const float*)d_in[2];
    const float* log_delta = (const float*)d_in[3];
    const float* log_r     = (const float*)d_in[4];
    float* out             = (float*)d_out;

    const int num_series = in_sizes[0] / TLEN;             // 32*1*128 = 4096
    const int waves_per_block = 4;                         // 256 threads
    const int grid = (num_series + waves_per_block - 1) / waves_per_block;

    pcen_kernel<<<grid, 256, 0, stream>>>(x, log_s, log_alpha, log_delta, log_r,
                                          out, num_series);
}

// Round 2
// 200.004 us; speedup vs baseline: 1.3350x; 1.3350x over previous
//
#include <hip/hip_runtime.h>

#define TLEN   6000
#define NV4    1500          // TLEN / 4 float4 groups per series
#define V4PT   4             // float4 per lane per tile
#define EPT    16            // elements per lane per tile
#define NTILES 6             // ceil(NV4 / (64*V4PT)) = ceil(1500/256)
#define EPS    1e-6f
#define LN_EPS (-13.815511f) // ln(1e-6)
#define INV_EPS 1e6f

__device__ __forceinline__ float pcen_full(float xv, float M, float alpha,
                                           float delta, float r, float deltar) {
    float gain = __expf(-alpha * (LN_EPS + __logf(fmaf(M, INV_EPS, 1.0f))));
    return __powf(fmaf(xv, gain, delta), r) - deltar;
}

__global__ __launch_bounds__(256, 4) void pcen_kernel(
    const float* __restrict__ x,
    const float* __restrict__ log_s,
    const float* __restrict__ log_alpha,
    const float* __restrict__ log_delta,
    const float* __restrict__ log_r,
    float* __restrict__ out,
    int num_series, int F)
{
    const int wave = (int)((blockIdx.x * blockDim.x + threadIdx.x) >> 6);
    const int lane = (int)(threadIdx.x & 63);
    if (wave >= num_series) return;

    const int f = wave % F;

    const float la = log_alpha[f], ld = log_delta[f], lr = log_r[f];
    const bool  triv = (la == 0.0f) && (ld == 0.0f) && (lr == 0.0f);

    const float s   = __expf(log_s[f]);
    const float oms = 1.0f - s;

    // oms powers: pw[k] = (1-s)^k, k=0..EPT (held in registers via full unroll)
    float pw[EPT + 1];
    pw[0] = 1.0f;
    #pragma unroll
    for (int k = 1; k <= EPT; ++k) pw[k] = pw[k - 1] * oms;
    const float oms4 = pw[4];

    // general-path params (cheap; unused on fast path)
    const float alpha  = __expf(la);
    const float delta  = __expf(ld);
    const float r      = __expf(lr);
    const float deltar = __powf(delta, r);

    const float4* __restrict__ xb = (const float4*)(x + (size_t)wave * TLEN);
    float4* __restrict__ ob       = (float4*)(out + (size_t)wave * TLEN);

    float Mc = 0.0f;   // smoother value entering current tile (0 before t=0: exact,
                       // because global element 0 uses coefficient 1 on x0)

    // preload tile 0: lane owns float4 indices 4*lane + j (time-contiguous block)
    float4 q[V4PT];
    {
        const int tb = 4 * lane;
        #pragma unroll
        for (int j = 0; j < V4PT; ++j)
            q[j] = (tb + j < NV4) ? xb[tb + j] : make_float4(0.f, 0.f, 0.f, 0.f);
    }

    for (int tile = 0; tile < NTILES; ++tile) {
        const int tb = tile * 256 + 4 * lane;

        // ---- prefetch next tile ----
        float4 p[V4PT];
        #pragma unroll
        for (int j = 0; j < V4PT; ++j) p[j] = make_float4(0.f, 0.f, 0.f, 0.f);
        if (tile + 1 < NTILES) {
            const int nb = tb + 256;
            #pragma unroll
            for (int j = 0; j < V4PT; ++j)
                if (nb + j < NV4) p[j] = xb[nb + j];
        }

        // ---- per-lane affine chain over its 16 contiguous timesteps ----
        // B_t = oms*B_{t-1} + s*x_t  (global first element: coeff 1 on x0)
        float Bv[EPT];
        float B = 0.0f, A = 1.0f;
        #pragma unroll
        for (int j = 0; j < V4PT; ++j) {
            const bool ok = (tb + j) < NV4;
            if (ok) {
                const float4 xq = q[j];
                const float c0 = (tile == 0 && lane == 0 && j == 0) ? 1.0f : s;
                B = fmaf(oms, B, c0 * xq.x); Bv[4 * j + 0] = B;
                B = fmaf(oms, B, s  * xq.y); Bv[4 * j + 1] = B;
                B = fmaf(oms, B, s  * xq.z); Bv[4 * j + 2] = B;
                B = fmaf(oms, B, s  * xq.w); Bv[4 * j + 3] = B;
                A *= oms4;
            }
        }

        // ---- inclusive wave scan of affine composition (lane order = time order) ----
        #pragma unroll
        for (int off = 1; off < 64; off <<= 1) {
            const float Ap = __shfl_up(A, off, 64);
            const float Bp = __shfl_up(B, off, 64);
            if (lane >= off) { B = fmaf(A, Bp, B); A = A * Ap; }
        }
        const float A63 = __shfl(A, 63, 64);
        const float B63 = __shfl(B, 63, 64);
        float Ae = __shfl_up(A, 1, 64);
        float Be = __shfl_up(B, 1, 64);
        if (lane == 0) { Ae = 1.0f; Be = 0.0f; }

        const float Min = fmaf(Ae, Mc, Be);   // smoother entering this lane's block

        // ---- epilogue: M_t = oms^(t+1) * Min + B_t ----
        if (triv) {
            // alpha=delta=r=1  =>  out = x / (eps + M)   (exact algebraic reduction)
            #pragma unroll
            for (int j = 0; j < V4PT; ++j) {
                if ((tb + j) < NV4) {
                    const float4 xq = q[j];
                    float4 o;
                    float m;
                    m = fmaf(pw[4 * j + 1], Min, Bv[4 * j + 0]);
                    o.x = xq.x * __builtin_amdgcn_rcpf(m + EPS);
                    m = fmaf(pw[4 * j + 2], Min, Bv[4 * j + 1]);
                    o.y = xq.y * __builtin_amdgcn_rcpf(m + EPS);
                    m = fmaf(pw[4 * j + 3], Min, Bv[4 * j + 2]);
                    o.z = xq.z * __builtin_amdgcn_rcpf(m + EPS);
                    m = fmaf(pw[4 * j + 4], Min, Bv[4 * j + 3]);
                    o.w = xq.w * __builtin_amdgcn_rcpf(m + EPS);
                    ob[tb + j] = o;
                }
            }
        } else {
            #pragma unroll
            for (int j = 0; j < V4PT; ++j) {
                if ((tb + j) < NV4) {
                    const float4 xq = q[j];
                    float4 o;
                    float m;
                    m = fmaf(pw[4 * j + 1], Min, Bv[4 * j + 0]);
                    o.x = pcen_full(xq.x, m, alpha, delta, r, deltar);
                    m = fmaf(pw[4 * j + 2], Min, Bv[4 * j + 1]);
                    o.y = pcen_full(xq.y, m, alpha, delta, r, deltar);
                    m = fmaf(pw[4 * j + 3], Min, Bv[4 * j + 2]);
                    o.z = pcen_full(xq.z, m, alpha, delta, r, deltar);
                    m = fmaf(pw[4 * j + 4], Min, Bv[4 * j + 3]);
                    o.w = pcen_full(xq.w, m, alpha, delta, r, deltar);
                    ob[tb + j] = o;
                }
            }
        }

        // ---- carry across tiles ----
        Mc = fmaf(A63, Mc, B63);
        #pragma unroll
        for (int j = 0; j < V4PT; ++j) q[j] = p[j];
    }
}

extern "C" void kernel_launch(void* const* d_in, const int* in_sizes, int n_in,
                              void* d_out, int out_size, void* d_ws, size_t ws_size,
                              hipStream_t stream) {
    const float* x         = (const float*)d_in[0];
    const float* log_s     = (const float*)d_in[1];
    const float* log_alpha = (const float*)d_in[2];
    const float* log_delta = (const float*)d_in[3];
    const float* log_r     = (const float*)d_in[4];
    float* out             = (float*)d_out;

    const int F = in_sizes[1];                 // 128 bands
    const int num_series = in_sizes[0] / TLEN; // 32*1*128 = 4096
    const int waves_per_block = 4;             // 256 threads
    const int grid = (num_series + waves_per_block - 1) / waves_per_block;

    pcen_kernel<<<grid, 256, 0, stream>>>(x, log_s, log_alpha, log_delta, log_r,
                                          out, num_series, F);
}

// Round 3
// 187.063 us; speedup vs baseline: 1.4274x; 1.0692x over previous
//
#include <hip/hip_runtime.h>

#define TLEN     6000
#define NV4      1500        // float4 groups per series
#define CHUNK_V4 256         // float4 per chunk = 1024 elements
#define NCHUNK   6           // ceil(NV4 / CHUNK_V4)
#define V4PL     4           // float4 per lane per chunk
#define EPT      16          // elements per lane
#define EPS      1e-6f
#define LN_EPS   (-13.815511f) // ln(1e-6)
#define INV_EPS  1e6f

__device__ __forceinline__ float pcen_full(float xv, float M, float alpha,
                                           float delta, float r, float deltar) {
    float gain = __expf(-alpha * (LN_EPS + __logf(fmaf(M, INV_EPS, 1.0f))));
    return __powf(fmaf(xv, gain, delta), r) - deltar;
}

// b^e for integer e in [0,63] — safe for negative b (unlike powf)
__device__ __forceinline__ float ipow6(float b, int e) {
    float r = 1.0f;
    #pragma unroll
    for (int i = 0; i < 6; ++i) {
        if (e & 1) r *= b;
        b *= b;
        e >>= 1;
    }
    return r;
}

__global__ __launch_bounds__(256, 4) void pcen_kernel(
    const float* __restrict__ x,
    const float* __restrict__ log_s,
    const float* __restrict__ log_alpha,
    const float* __restrict__ log_delta,
    const float* __restrict__ log_r,
    float* __restrict__ out,
    int num_series, int F)
{
    const int g    = (int)((blockIdx.x * blockDim.x + threadIdx.x) >> 6);
    const int lane = (int)(threadIdx.x & 63);
    if (g >= num_series * NCHUNK) return;
    const int series = g / NCHUNK;
    const int c      = g - series * NCHUNK;   // chunk index within series
    const int f      = series % F;

    const float la = log_alpha[f], ld = log_delta[f], lr = log_r[f];
    const bool  triv = (la == 0.0f) && (ld == 0.0f) && (lr == 0.0f);

    const float s    = __expf(log_s[f]);
    const float oms  = 1.0f - s;

    // pw[k] = oms^k, k=0..16
    float pw[EPT + 1];
    pw[0] = 1.0f;
    #pragma unroll
    for (int k = 1; k <= EPT; ++k) pw[k] = pw[k - 1] * oms;
    const float oms4  = pw[4];
    const float omsP  = pw[16];            // oms^16 = per-lane decay (full lane)

    // chunk-total decay A_chunk = oms^1024 = omsP^64 (6 squarings)
    float A_chunk = omsP;
    #pragma unroll
    for (int i = 0; i < 6; ++i) A_chunk *= A_chunk;
    // runtime guard: is one warm-up chunk enough to reconstruct the carry?
    const bool decay_ok = fabsf(A_chunk) < 1e-7f;

    // per-lane weight for warm-chunk total: w_l = omsP^(63-lane)
    const float wl = ipow6(omsP, 63 - lane);

    // general-path params
    const float alpha  = __expf(la);
    const float delta  = __expf(ld);
    const float r      = __expf(lr);
    const float deltar = __powf(delta, lr == 0.0f ? 1.0f : r);

    const float4* __restrict__ xb = (const float4*)(x + (size_t)series * TLEN);
    float4* __restrict__ ob       = (float4*)(out + (size_t)series * TLEN);

    // ---- issue ALL fast-path loads up front (8 independent float4 loads) ----
    const int tb = c * CHUNK_V4 + 4 * lane;           // main-chunk float4 base
    const int wb = (c - 1) * CHUNK_V4 + 4 * lane;     // warm-chunk float4 base
    float4 wq[V4PL], q[V4PL];
    if (c > 0) {                                      // warm chunk always fully in-bounds
        #pragma unroll
        for (int j = 0; j < V4PL; ++j) wq[j] = xb[wb + j];
    }
    #pragma unroll
    for (int j = 0; j < V4PL; ++j)
        q[j] = (tb + j < NV4) ? xb[tb + j] : make_float4(0.f, 0.f, 0.f, 0.f);

    float Mc = 0.0f;   // smoother entering main chunk

    // ---- exact fallback: if decay too slow, accumulate ALL earlier chunks ----
    if (!decay_ok) {
        for (int wc = 0; wc + 1 < c; ++wc) {
            const int b0 = wc * CHUNK_V4 + 4 * lane;
            float B = 0.0f;
            #pragma unroll
            for (int j = 0; j < V4PL; ++j) {
                const float4 xq = xb[b0 + j];
                const float c0 = (wc == 0 && lane == 0 && j == 0) ? 1.0f : s;
                B = fmaf(oms, B, c0 * xq.x);
                B = fmaf(oms, B, s  * xq.y);
                B = fmaf(oms, B, s  * xq.z);
                B = fmaf(oms, B, s  * xq.w);
            }
            float v = wl * B;
            #pragma unroll
            for (int off = 1; off < 64; off <<= 1)
                v += __shfl_xor(v, off, 64);
            Mc = fmaf(A_chunk, Mc, v);
        }
    }

    // ---- warm chunk c-1 (prefetched): chain + weighted wave-reduce ----
    if (c > 0) {
        float B = 0.0f;
        #pragma unroll
        for (int j = 0; j < V4PL; ++j) {
            const float4 xq = wq[j];
            const float c0 = (c == 1 && lane == 0 && j == 0) ? 1.0f : s;
            B = fmaf(oms, B, c0 * xq.x);
            B = fmaf(oms, B, s  * xq.y);
            B = fmaf(oms, B, s  * xq.z);
            B = fmaf(oms, B, s  * xq.w);
        }
        float v = wl * B;
        #pragma unroll
        for (int off = 1; off < 64; off <<= 1)
            v += __shfl_xor(v, off, 64);
        Mc = fmaf(A_chunk, Mc, v);
    }

    // ---- main chunk: per-lane chain with stored prefixes ----
    float Bv[EPT];
    float B = 0.0f, A = 1.0f;
    #pragma unroll
    for (int j = 0; j < V4PL; ++j) {
        if (tb + j < NV4) {
            const float4 xq = q[j];
            const float c0 = (c == 0 && lane == 0 && j == 0) ? 1.0f : s;
            B = fmaf(oms, B, c0 * xq.x); Bv[4 * j + 0] = B;
            B = fmaf(oms, B, s  * xq.y); Bv[4 * j + 1] = B;
            B = fmaf(oms, B, s  * xq.z); Bv[4 * j + 2] = B;
            B = fmaf(oms, B, s  * xq.w); Bv[4 * j + 3] = B;
            A *= oms4;
        }
    }

    // inclusive wave scan of affine composition (lane order = time order)
    #pragma unroll
    for (int off = 1; off < 64; off <<= 1) {
        const float Ap = __shfl_up(A, off, 64);
        const float Bp = __shfl_up(B, off, 64);
        if (lane >= off) { B = fmaf(A, Bp, B); A = A * Ap; }
    }
    float Ae = __shfl_up(A, 1, 64);
    float Be = __shfl_up(B, 1, 64);
    if (lane == 0) { Ae = 1.0f; Be = 0.0f; }

    const float Min = fmaf(Ae, Mc, Be);   // smoother entering this lane's block

    // ---- epilogue: M_t = oms^(t+1) * Min + B_t ----
    if (triv) {
        // alpha=delta=r=1  =>  out = x / (eps + M)  (exact algebraic reduction)
        #pragma unroll
        for (int j = 0; j < V4PL; ++j) {
            if (tb + j < NV4) {
                const float4 xq = q[j];
                float4 o; float m;
                m = fmaf(pw[4 * j + 1], Min, Bv[4 * j + 0]);
                o.x = xq.x * __builtin_amdgcn_rcpf(m + EPS);
                m = fmaf(pw[4 * j + 2], Min, Bv[4 * j + 1]);
                o.y = xq.y * __builtin_amdgcn_rcpf(m + EPS);
                m = fmaf(pw[4 * j + 3], Min, Bv[4 * j + 2]);
                o.z = xq.z * __builtin_amdgcn_rcpf(m + EPS);
                m = fmaf(pw[4 * j + 4], Min, Bv[4 * j + 3]);
                o.w = xq.w * __builtin_amdgcn_rcpf(m + EPS);
                ob[tb + j] = o;
            }
        }
    } else {
        #pragma unroll
        for (int j = 0; j < V4PL; ++j) {
            if (tb + j < NV4) {
                const float4 xq = q[j];
                float4 o; float m;
                m = fmaf(pw[4 * j + 1], Min, Bv[4 * j + 0]);
                o.x = pcen_full(xq.x, m, alpha, delta, r, deltar);
                m = fmaf(pw[4 * j + 2], Min, Bv[4 * j + 1]);
                o.y = pcen_full(xq.y, m, alpha, delta, r, deltar);
                m = fmaf(pw[4 * j + 3], Min, Bv[4 * j + 2]);
                o.z = pcen_full(xq.z, m, alpha, delta, r, deltar);
                m = fmaf(pw[4 * j + 4], Min, Bv[4 * j + 3]);
                o.w = pcen_full(xq.w, m, alpha, delta, r, deltar);
                ob[tb + j] = o;
            }
        }
    }
}

extern "C" void kernel_launch(void* const* d_in, const int* in_sizes, int n_in,
                              void* d_out, int out_size, void* d_ws, size_t ws_size,
                              hipStream_t stream) {
    const float* x         = (const float*)d_in[0];
    const float* log_s     = (const float*)d_in[1];
    const float* log_alpha = (const float*)d_in[2];
    const float* log_delta = (const float*)d_in[3];
    const float* log_r     = (const float*)d_in[4];
    float* out             = (float*)d_out;

    const int F = in_sizes[1];                 // 128 bands
    const int num_series = in_sizes[0] / TLEN; // 4096
    const int num_waves  = num_series * NCHUNK;
    const int num_threads = num_waves * 64;
    const int grid = (num_threads + 255) / 256;

    pcen_kernel<<<grid, 256, 0, stream>>>(x, log_s, log_alpha, log_delta, log_r,
                                          out, num_series, F);
}